// Round 13
// baseline (157.579 us; speedup 1.0000x reference)
//
#include <hip/hip_runtime.h>

// Bilateral filter, fixed shape: x[16,3,512,512] fp32, K=5, pad=2 reflect.
// sigma_color = sigma_space = 1.1; normalizations cancel in the ratio.
// w = exp2(coef2*(s+d^2)), coef2 = -log2(e)/2.42, s=(di-2)^2+(dj-2)^2.
//
// R10: measured verdicts: pk_f32 asm corrupts (R7/R8); __half2 gave NO
// packed speedup (R9: 58.4us > 53.8us scalar; 4147 cyc/wave vs 2500 ideal
// -> scalarized + pack/unpack overhead). Invariant across all measured
// kernels: 18 issue-cyc per px*tap (5 VALU*2 + 1 v_exp_f32*8), ~71%
// VALUBusy, issue-bound. This round removes the TRANS op entirely:
//   w = Ws * P(d^2),  P = deg-3 Chebyshev-node poly of exp2(coef2*u)
//   on u=[0,1] (max rel err ~1.4e-5), Ws = exp2(coef2*s) folded into
//   the 4 coefficients per tap class at COMPILE time (5 classes).
// Per px*tap: sub, mul, 3 fma (Horner), fma(num), add(den) = 7 VALU
// = 14 cyc vs 18 -> predict dispatch 53.8 -> ~43 us.
// Error budget: weight rel err 2e-5 -> output err ~2e-5, invisible vs
// 0.0039 measured floor and 0.0172 threshold.
//
// One thread = 4x2 px tile; 6x8 f32 register window; center tap (w=1
// exact) folded into accumulator init. Plain scalar f32 (R6-verified
// structure), no v2f, no pins, no inline asm.
// Column reflect (verified R2-R4):
//   w0==0  : col -2 -> c4.z (col 2), col -1 -> l2.y (col 1)
//   w0==508: col 512 -> r2.x (col 510), col 513 -> c4.y (col 509)
// Row reflect: r = min(abs(r), 2*(H-1)-r).

constexpr int H_ = 512;
constexpr int W_ = 512;

// P(u) ~= exp2(coef2*u) on [0,1]; Chebyshev-node cubic interpolant.
// Audit: P(0)=0.999993, P(0.5)=0.813329 (true 0.813335), P(1)=0.661509
// (true 0.661510).
constexpr float PC0 = 0.999993f;
constexpr float PC1 = -0.412972f;
constexpr float PC2 = 0.0840929f;
constexpr float PC3 = -0.0096052f;

// WS[s] = exp2(coef2*s) = e^(-0.41322315*s) for s in {1,2,4,5,8}.
// Audit: ws1=e^-0.413223, ws2=ws1^2, ws4=ws2^2, ws5=ws4*ws1, ws8=ws4^2.
__device__ constexpr float WS_of(int s) {
    return s == 1 ? 0.6615123f
         : s == 2 ? 0.4376019f
         : s == 4 ? 0.1914962f
         : s == 5 ? 0.1266760f
         :          0.0366697f;   // s == 8
}

__global__ __launch_bounds__(256, 4) void bilateral_kernel(
    const float* __restrict__ x,
    float* __restrict__ out,
    int nthreads)
{
    int t = blockIdx.x * 256 + threadIdx.x;
    if (t >= nthreads) return;

    int qx = t & 127;          // tile col index (4-wide tiles)
    int rg = (t >> 7) & 255;   // tile row index (2-tall tiles)
    int pl = t >> 15;          // plane (b*C + c)
    int w0 = qx << 2;
    int h0 = rg << 1;
    const float* plane = x + ((long)pl << 18);   // 512*512
    float* oplane = out + ((long)pl << 18);

    int aL = max(w0 - 2, 0);
    int aR = min(w0 + 4, W_ - 2);
    bool bL = (w0 == 0);
    bool bR = (w0 == W_ - 4);

    // 6x8 window: rows h0-2..h0+3, cols w0-2..w0+5.
    float Wn[6][8];
#pragma unroll
    for (int k = 0; k < 6; ++k) {
        int r = h0 + k - 2;
        r = min(abs(r), 2 * (H_ - 1) - r);
        const float* rp = plane + r * W_;
        float2 l2 = *(const float2*)(rp + aL);
        float4 c4 = *(const float4*)(rp + w0);
        float2 r2 = *(const float2*)(rp + aR);
        Wn[k][0] = bL ? c4.z : l2.x;   // reflect col -2 -> +2
        Wn[k][1] = l2.y;               // col -1 (== col 1 when bL)
        Wn[k][2] = c4.x; Wn[k][3] = c4.y; Wn[k][4] = c4.z; Wn[k][5] = c4.w;
        Wn[k][6] = r2.x;               // col +4 (== col 510 when bR)
        Wn[k][7] = bR ? c4.y : r2.y;   // reflect col 513 -> 509
    }

#pragma unroll
    for (int oi = 0; oi < 2; ++oi) {
        float c0 = Wn[oi + 2][2], c1 = Wn[oi + 2][3];
        float c2 = Wn[oi + 2][4], c3 = Wn[oi + 2][5];
        // Center tap folded exactly: w = 1.
        float num0 = c0, num1 = c1, num2 = c2, num3 = c3;
        float den0 = 1.f, den1 = 1.f, den2 = 1.f, den3 = 1.f;
#pragma unroll
        for (int di = 0; di < 5; ++di) {
#pragma unroll
            for (int dj = 0; dj < 5; ++dj) {
                if (di == 2 && dj == 2) continue;   // center handled above
                const int s = (di - 2) * (di - 2) + (dj - 2) * (dj - 2);
                const float K3 = WS_of(s) * PC3;    // compile-time folds
                const float K2 = WS_of(s) * PC2;
                const float K1 = WS_of(s) * PC1;
                const float K0 = WS_of(s) * PC0;
                const float* row = Wn[oi + di];
                // 4 output pixels share the tap-class constants.
                {
                    float p = row[0 + dj];
                    float d = p - c0;
                    float u = d * d;
                    float w = __builtin_fmaf(
                        __builtin_fmaf(__builtin_fmaf(K3, u, K2), u, K1),
                        u, K0);
                    num0 = __builtin_fmaf(w, p, num0);
                    den0 += w;
                }
                {
                    float p = row[1 + dj];
                    float d = p - c1;
                    float u = d * d;
                    float w = __builtin_fmaf(
                        __builtin_fmaf(__builtin_fmaf(K3, u, K2), u, K1),
                        u, K0);
                    num1 = __builtin_fmaf(w, p, num1);
                    den1 += w;
                }
                {
                    float p = row[2 + dj];
                    float d = p - c2;
                    float u = d * d;
                    float w = __builtin_fmaf(
                        __builtin_fmaf(__builtin_fmaf(K3, u, K2), u, K1),
                        u, K0);
                    num2 = __builtin_fmaf(w, p, num2);
                    den2 += w;
                }
                {
                    float p = row[3 + dj];
                    float d = p - c3;
                    float u = d * d;
                    float w = __builtin_fmaf(
                        __builtin_fmaf(__builtin_fmaf(K3, u, K2), u, K1),
                        u, K0);
                    num3 = __builtin_fmaf(w, p, num3);
                    den3 += w;
                }
            }
        }
        float4 o;
        o.x = num0 * __builtin_amdgcn_rcpf(den0);
        o.y = num1 * __builtin_amdgcn_rcpf(den1);
        o.z = num2 * __builtin_amdgcn_rcpf(den2);
        o.w = num3 * __builtin_amdgcn_rcpf(den3);
        *(float4*)(oplane + (h0 + oi) * W_ + w0) = o;
    }
}

extern "C" void kernel_launch(void* const* d_in, const int* in_sizes, int n_in,
                              void* d_out, int out_size, void* d_ws, size_t ws_size,
                              hipStream_t stream)
{
    const float* x = (const float*)d_in[0];
    float* out = (float*)d_out;
    int nthreads = in_sizes[0] >> 3;         // 8 px per thread (4x2 tile)
    int blocks = (nthreads + 255) / 256;
    bilateral_kernel<<<blocks, 256, 0, stream>>>(x, out, nthreads);
}